// Round 7
// baseline (49.690 us; speedup 1.0000x reference)
//
#include <hip/hip_runtime.h>
#include <math.h>

#define BLKSZ 160
#define NWT   64
#define WTLEN 512
#define FPB   16      // frames per main block
#define SPB   2560    // samples per main block (16*160)

// ReduceWindowRewriter(base_length=16) level sizes for T=960000
#define NB0   60000   // block sums level 0: T/16
#define NB1   3750    // NB0/16
#define NB1P  3760    // padded to 235*16
#define NB2   235
#define NB2P  240     // padded to 15*16
#define NB3   15      // < 16 -> naive sequential scan

// f32 increment exactly as the reference: (pitch / 16000) * 512
static __device__ __forceinline__ float inc32_of(float p) {
    return (p / 16000.0f) * 512.0f;
}

// K0: effective wavetables: rows 0..3 raw, rows 4..63 tanh
__global__ void k_wts_eff(const float* __restrict__ wts, float* __restrict__ wts_eff, int n) {
    int i = blockIdx.x * blockDim.x + threadIdx.x;
    if (i >= n) return;
    float v = wts[i];
    if ((i >> 9) >= 4) v = tanhf(v);
    wts_eff[i] = v;
}

// K1: bs0[j] = sequential f32 sum of incs 16j..16j+15
__global__ __launch_bounds__(256) void k_bs0(const float* __restrict__ pitch,
                                             float* __restrict__ bs0) {
    int j = blockIdx.x * blockDim.x + threadIdx.x;
    if (j >= NB0) return;
    const float4* p4 = (const float4*)(pitch + (size_t)j * 16);
    float acc = 0.f;
    #pragma unroll
    for (int i = 0; i < 4; ++i) {
        float4 v = p4[i];
        acc = acc + inc32_of(v.x);
        acc = acc + inc32_of(v.y);
        acc = acc + inc32_of(v.z);
        acc = acc + inc32_of(v.w);
    }
    bs0[j] = acc;
}

// K2: one block computes levels 1..4 and writes S1[NB0] (inclusive scan of bs0)
__global__ __launch_bounds__(1024) void k_levels(const float* __restrict__ bs0,
                                                 float* __restrict__ S1) {
    __shared__ float bs1L[NB1P];    // 15040 B (zero-padded)
    __shared__ float bs2L[NB2P];    // 960 B   (zero-padded)
    __shared__ float bs3L[16];
    __shared__ float S4L[16];
    __shared__ float S3L[NB2];      // 940 B
    __shared__ float S2L[NB1];      // 15000 B
    int tid = threadIdx.x;

    // bs1: rows of 16 over bs0
    for (int j = tid; j < NB1P; j += 1024) {
        float a = 0.f;
        if (j < NB1) {
            const float* s = bs0 + (size_t)j * 16;
            for (int i = 0; i < 16; ++i) a = a + s[i];
        }
        bs1L[j] = a;
    }
    __syncthreads();
    // bs2: rows of 16 over padded bs1
    if (tid < NB2P) {
        float a = 0.f;
        if (tid < NB2) {
            for (int i = 0; i < 16; ++i) a = a + bs1L[tid * 16 + i];
        }
        bs2L[tid] = a;
    }
    __syncthreads();
    // bs3: rows of 16 over padded bs2
    if (tid < 16) {
        float a = 0.f;
        if (tid < NB3) {
            for (int i = 0; i < 16; ++i) a = a + bs2L[tid * 16 + i];
        }
        bs3L[tid] = a;
    }
    __syncthreads();
    // S4: naive sequential inclusive scan of bs3 (length 15 < base)
    if (tid == 0) {
        float a = 0.f;
        for (int i = 0; i < NB3; ++i) { a = a + bs3L[i]; S4L[i] = a; }
    }
    __syncthreads();
    // S3[j] = inner3 + off4 ; inner3 = seq prefix within padded-bs2 row
    if (tid < NB2) {
        int r = tid >> 4, i = tid & 15;
        float a = 0.f;
        for (int k = 0; k <= i; ++k) a = a + bs2L[r * 16 + k];
        S3L[tid] = r ? (a + S4L[r - 1]) : a;
    }
    __syncthreads();
    // S2[j] = inner2 + off3
    for (int j = tid; j < NB1; j += 1024) {
        int r = j >> 4, i = j & 15;
        float a = 0.f;
        for (int k = 0; k <= i; ++k) a = a + bs1L[r * 16 + k];
        S2L[j] = r ? (a + S3L[r - 1]) : a;
    }
    __syncthreads();
    // S1: per row r of bs0: running seq prefix, each + off2 (separate add!)
    for (int r = tid; r < NB1; r += 1024) {
        float off = r ? S2L[r - 1] : 0.f;
        const float* s = bs0 + (size_t)r * 16;
        float acc = 0.f;
        for (int i = 0; i < 16; ++i) {
            acc = acc + s[i];
            S1[r * 16 + i] = r ? (acc + off) : acc;
        }
    }
}

// K3: fused softmax -> mixrow -> per-sample 16-chain + offset -> lerp -> amp
__global__ __launch_bounds__(512) void k_main(
    const float* __restrict__ pitch, const float* __restrict__ amp,
    const float* __restrict__ att, const float* __restrict__ wts_eff,
    const float* __restrict__ S1, float* __restrict__ out, int frames)
{
    __shared__ float sm[FPB][NWT];          // 4 KB
    __shared__ float mixrow[FPB][WTLEN];    // 32 KB
    __shared__ float incL[SPB];             // 10 KB
    __shared__ float roffL[SPB / 16];       // 160 rows: off1 per local row

    int tid = threadIdx.x, lane = tid & 63, wv = tid >> 6;
    int f0 = blockIdx.x * FPB;
    size_t base = (size_t)blockIdx.x * SPB;
    int R0 = blockIdx.x * (SPB / 16);

    // softmax: 8 waves x 2 frames
    #pragma unroll
    for (int r = 0; r < 2; ++r) {
        int f = f0 + wv * 2 + r;
        float a = att[(size_t)lane * frames + f];
        float m = a;
        #pragma unroll
        for (int off = 32; off; off >>= 1) m = fmaxf(m, __shfl_xor(m, off, 64));
        float e = expf(a - m);
        float s = e;
        #pragma unroll
        for (int off = 32; off; off >>= 1) s += __shfl_xor(s, off, 64);
        sm[wv * 2 + r][lane] = e / s;
    }
    if (tid < SPB / 16) {
        int rg = R0 + tid;
        roffL[tid] = rg ? S1[rg - 1] : 0.f;   // fl(x+0)=x: exact for row 0
    }
    __syncthreads();

    // mixrow[f][j] = sum_w sm[f][w] * wts_eff[w][j]
    {
        float acc[FPB];
        #pragma unroll
        for (int k = 0; k < FPB; ++k) acc[k] = 0.f;
        for (int w = 0; w < NWT; ++w) {
            float v = wts_eff[w * WTLEN + tid];
            #pragma unroll
            for (int k = 0; k < FPB; ++k) acc[k] += sm[k][w] * v;
        }
        #pragma unroll
        for (int k = 0; k < FPB; ++k) mixrow[k][tid] = acc[k];
    }

    // stage incs
    #pragma unroll
    for (int i = 0; i < SPB / 512; ++i)
        incL[i * 512 + tid] = inc32_of(pitch[base + i * 512 + tid]);
    __syncthreads();

    // per-sample: inner0 = seq prefix of its 16-row; C = fl(inner0 + off1)
    #pragma unroll
    for (int i = 0; i < SPB / 512; ++i) {
        int tl = i * 512 + tid;
        int row = tl >> 4, lanei = tl & 15, b = row << 4;
        float acc = incL[b];
        for (int j = 1; j <= lanei; ++j) acc = acc + incL[b + j];
        float C = acc + roffL[row];           // off=0 exact for global row 0
        float incv = incL[tl];
        float sub = C - incv;
        float idx = fmodf(sub, 512.0f);
        if (idx < 0.f) idx += 512.f;
        int li = (int)idx;
        float alpha = idx - (float)li;
        int hi = ((int)ceilf(idx)) & (WTLEN - 1);
        int fr = tl / BLKSZ;
        float wlo = mixrow[fr][li];
        float whi = mixrow[fr][hi];
        out[base + tl] = (wlo + alpha * (whi - wlo)) * amp[base + tl];
    }
}

extern "C" void kernel_launch(void* const* d_in, const int* in_sizes, int n_in,
                              void* d_out, int out_size, void* d_ws, size_t ws_size,
                              hipStream_t stream) {
    const float* pitch = (const float*)d_in[0];
    const float* amp   = (const float*)d_in[1];
    const float* wts   = (const float*)d_in[2];
    const float* att   = (const float*)d_in[3];

    int T      = in_sizes[0];        // 960000
    int frames = T / BLKSZ;          // 6000
    int nmain  = T / SPB;            // 375

    float* ws      = (float*)d_ws;
    float* wts_eff = ws;                       // 32768 floats
    float* bs0     = ws + 32768;               // NB0 floats
    float* S1      = ws + 32768 + NB0;         // NB0 floats
    float* out     = (float*)d_out;

    k_wts_eff<<<(NWT * WTLEN + 255) / 256, 256, 0, stream>>>(wts, wts_eff, NWT * WTLEN);
    k_bs0    <<<(NB0 + 255) / 256, 256, 0, stream>>>(pitch, bs0);
    k_levels <<<1, 1024, 0, stream>>>(bs0, S1);
    k_main   <<<nmain, 512, 0, stream>>>(pitch, amp, att, wts_eff, S1, out, frames);
}

// Round 8
// 30.901 us; speedup vs baseline: 1.6080x; 1.6080x over previous
//
#include <hip/hip_runtime.h>
#include <math.h>

#define BLKSZ 160
#define NWT   64
#define WTLEN 512
#define FPB   16      // frames per main block
#define SPB   2560    // samples per main block (16*160)

// ReduceWindowRewriter(base_length=16) level sizes for T=960000
#define NB0   60000   // T/16
#define NB1   3750    // NB0/16
#define NB2   235     // ceil(NB1/16)
#define NB2P  240
#define NB3   15      // < 16 -> naive sequential top scan

// f32 increment exactly as the reference: (pitch / 16000) * 512
static __device__ __forceinline__ float inc32_of(float p) {
    return (p / 16000.0f) * 512.0f;
}

// K1: leaf levels. blocks [0,235): per-4096-sample tree -> bs1 (16), bs2 (1).
//     blocks [235,363): wts_eff (rows 0..3 raw, 4..63 tanh).
__global__ __launch_bounds__(256) void k_leaf(
    const float* __restrict__ pitch, const float* __restrict__ wts,
    float* __restrict__ bs1, float* __restrict__ bs2,
    float* __restrict__ wts_eff, int T)
{
    int t = threadIdx.x;
    if (blockIdx.x >= NB2) {                      // wts_eff part
        int i = (blockIdx.x - NB2) * 256 + t;
        if (i < NWT * WTLEN) {
            float v = wts[i];
            if ((i >> 9) >= 4) v = tanhf(v);
            wts_eff[i] = v;
        }
        return;
    }
    __shared__ float b0[256];
    __shared__ float b1[16];
    int blk = blockIdx.x;
    size_t s0 = (size_t)blk * 4096;
    int nsamp = min(4096, T - (int)s0);
    int nb0 = nsamp >> 4;                         // 256 or 96
    if (t < nb0) {                                // bs0: seq 16-chain of incs
        const float4* p4 = (const float4*)(pitch + s0 + (size_t)t * 16);
        float acc = 0.f;
        #pragma unroll
        for (int i = 0; i < 4; ++i) {
            float4 v = p4[i];
            acc = acc + inc32_of(v.x);
            acc = acc + inc32_of(v.y);
            acc = acc + inc32_of(v.z);
            acc = acc + inc32_of(v.w);
        }
        b0[t] = acc;
    }
    __syncthreads();
    int nb1 = nb0 >> 4;                           // 16 or 6
    if (t < nb1) {                                // bs1: seq 16-chain of bs0
        float acc = b0[t * 16];
        for (int j = 1; j < 16; ++j) acc = acc + b0[t * 16 + j];
        b1[t] = acc;
        bs1[blk * 16 + t] = acc;
    }
    __syncthreads();
    if (t == 0) {                                 // bs2: seq chain (pad zeros exact)
        float acc = b1[0];
        for (int j = 1; j < nb1; ++j) acc = acc + b1[j];
        bs2[blk] = acc;
    }
}

// K2: mid levels: bs2 -> bs3 -> S4 -> S3 -> S2  (single small block)
__global__ __launch_bounds__(512) void k_mid(const float* __restrict__ bs1,
                                             const float* __restrict__ bs2,
                                             float* __restrict__ S2)
{
    __shared__ float bs1L[NB1];     // 15000 B
    __shared__ float bs2L[NB2P];    // zero-padded
    __shared__ float bs3L[NB3];
    __shared__ float S4L[NB3];
    __shared__ float S3L[NB2];
    int t = threadIdx.x;
    for (int j = t; j < NB1; j += 512) bs1L[j] = bs1[j];
    if (t < NB2P) bs2L[t] = (t < NB2) ? bs2[t] : 0.f;
    __syncthreads();
    if (t < NB3) {                                // bs3: seq 16-chain of bs2
        float acc = bs2L[t * 16];
        for (int j = 1; j < 16; ++j) acc = acc + bs2L[t * 16 + j];
        bs3L[t] = acc;
    }
    __syncthreads();
    if (t == 0) {                                 // S4: naive seq scan (15 < 16)
        float acc = 0.f;
        for (int i = 0; i < NB3; ++i) { acc = acc + bs3L[i]; S4L[i] = acc; }
    }
    __syncthreads();
    if (t < NB2) {                                // S3 = inner3 + off4
        int r = t >> 4, i = t & 15;
        float acc = bs2L[r * 16];
        for (int k = 1; k <= i; ++k) acc = acc + bs2L[r * 16 + k];
        S3L[t] = r ? (acc + S4L[r - 1]) : acc;
    }
    __syncthreads();
    if (t < NB2) {                                // S2 row r: running prefix + off3
        float off = t ? S3L[t - 1] : 0.f;
        float acc = 0.f;
        int n = min(16, NB1 - t * 16);
        for (int i = 0; i < n; ++i) {
            acc = acc + bs1L[t * 16 + i];
            S2[t * 16 + i] = t ? (acc + off) : acc;
        }
    }
}

// K3: fused softmax -> mixrow -> local row-prefixes + local inner1/roff -> lerp -> amp
__global__ __launch_bounds__(512) void k_main(
    const float* __restrict__ pitch, const float* __restrict__ amp,
    const float* __restrict__ att, const float* __restrict__ wts_eff,
    const float* __restrict__ bs1, const float* __restrict__ S2,
    float* __restrict__ out, int frames)
{
    __shared__ float sm[FPB][NWT];          // 4 KB
    __shared__ float mixrow[FPB][WTLEN];    // 32 KB
    __shared__ float pr[SPB];               // 10 KB: inc -> within-16 prefix in place
    __shared__ float roffL[SPB / 16];       // 160
    __shared__ float S2w[11];               // S2[10b-2 .. 10b+8]
    __shared__ float bs1prev;               // bs1[10b-1]

    int tid = threadIdx.x, lane = tid & 63, wv = tid >> 6;
    int b = blockIdx.x;
    int f0 = b * FPB;
    size_t base = (size_t)b * SPB;

    // softmax: 8 waves x 2 frames
    #pragma unroll
    for (int r = 0; r < 2; ++r) {
        int f = f0 + wv * 2 + r;
        float a = att[(size_t)lane * frames + f];
        float m = a;
        #pragma unroll
        for (int off = 32; off; off >>= 1) m = fmaxf(m, __shfl_xor(m, off, 64));
        float e = expf(a - m);
        float s = e;
        #pragma unroll
        for (int off = 32; off; off >>= 1) s += __shfl_xor(s, off, 64);
        sm[wv * 2 + r][lane] = e / s;
    }
    if (tid < 11) {
        int g = 10 * b - 2 + tid;
        S2w[tid] = (g >= 0) ? S2[g] : 0.f;
    }
    if (tid == 11) bs1prev = (b > 0) ? bs1[10 * b - 1] : 0.f;

    // stage incs (keep in regs), before the sync that publishes sm
    float increg[SPB / 512];
    #pragma unroll
    for (int i = 0; i < SPB / 512; ++i) {
        increg[i] = inc32_of(pitch[base + i * 512 + tid]);
        pr[i * 512 + tid] = increg[i];
    }
    __syncthreads();

    // mixrow[f][j] = sum_w sm[f][w] * wts_eff[w][j]
    {
        float acc[FPB];
        #pragma unroll
        for (int k = 0; k < FPB; ++k) acc[k] = 0.f;
        for (int w = 0; w < NWT; ++w) {
            float v = wts_eff[w * WTLEN + tid];
            #pragma unroll
            for (int k = 0; k < FPB; ++k) acc[k] += sm[k][w] * v;
        }
        #pragma unroll
        for (int k = 0; k < FPB; ++k) mixrow[k][tid] = acc[k];
    }
    __syncthreads();   // pr staged + mixrow published

    // within-16 inclusive prefixes, in place (same chain order as ref level 0)
    if (tid < SPB / 16) {
        int bofs = tid * 16;
        float acc = pr[bofs];
        for (int j = 1; j < 16; ++j) { acc = acc + pr[bofs + j]; pr[bofs + j] = acc; }
    }
    __syncthreads();

    // roffL[t] = S1[R0 + t - 1]  (S1 = scan of bs0), recomputed locally
    if (tid < SPB / 16) {
        float v;
        if (tid == 0) {
            v = (b == 0) ? 0.f : (bs1prev + S2w[0]);      // full-row inner1 = bs1
        } else {
            int lr = (tid - 1) >> 4;                      // local bs1-row 0..9
            int p  = (tid - 1) & 15;
            float acc = pr[(lr * 16) * 16 + 15];          // local bs0 via row prefix
            for (int q = 1; q <= p; ++q) acc = acc + pr[(lr * 16 + q) * 16 + 15];
            int gr = 10 * b + lr;
            v = gr ? (acc + S2w[lr + 1]) : acc;           // S2w[lr+1] = S2[gr-1]
        }
        roffL[tid] = v;
    }
    __syncthreads();

    // per-sample: C = fl(prefix + roff); idx = (C - inc) % 512; lerp; amplitude
    #pragma unroll
    for (int i = 0; i < SPB / 512; ++i) {
        int tl = i * 512 + tid;
        size_t tg = base + tl;
        float C = pr[tl] + roffL[tl >> 4];
        float sub = C - increg[i];
        float idx = fmodf(sub, 512.0f);
        if (idx < 0.f) idx += 512.f;
        int li = (int)idx;
        float alpha = idx - (float)li;
        int hi = ((int)ceilf(idx)) & (WTLEN - 1);
        int fr = tl / BLKSZ;
        float wlo = mixrow[fr][li];
        float whi = mixrow[fr][hi];
        out[tg] = (wlo + alpha * (whi - wlo)) * amp[tg];
    }
}

extern "C" void kernel_launch(void* const* d_in, const int* in_sizes, int n_in,
                              void* d_out, int out_size, void* d_ws, size_t ws_size,
                              hipStream_t stream) {
    const float* pitch = (const float*)d_in[0];
    const float* amp   = (const float*)d_in[1];
    const float* wts   = (const float*)d_in[2];
    const float* att   = (const float*)d_in[3];

    int T      = in_sizes[0];        // 960000
    int frames = T / BLKSZ;          // 6000
    int nmain  = T / SPB;            // 375

    float* ws      = (float*)d_ws;
    float* wts_eff = ws;                     // 32768
    float* bs1     = ws + 32768;             // 3750 (pad 3840)
    float* bs2     = ws + 32768 + 3840;      // 235  (pad 256)
    float* S2      = ws + 32768 + 3840 + 256;// 3750
    float* out     = (float*)d_out;

    int nwts_blocks = (NWT * WTLEN + 255) / 256;       // 128
    k_leaf<<<NB2 + nwts_blocks, 256, 0, stream>>>(pitch, wts, bs1, bs2, wts_eff, T);
    k_mid <<<1, 512, 0, stream>>>(bs1, bs2, S2);
    k_main<<<nmain, 512, 0, stream>>>(pitch, amp, att, wts_eff, bs1, S2, out, frames);
}